// Round 3
// baseline (5472.310 us; speedup 1.0000x reference)
//
#include <hip/hip_runtime.h>
#include <hip/hip_bf16.h>
#include <stdint.h>

typedef _Float16 f16;
typedef _Float16 f16x8 __attribute__((ext_vector_type(8)));
typedef float f32x4 __attribute__((ext_vector_type(4)));

#define B_SZ 4096
#define HID  1024
#define LAT  128
#define OBS  64
#define TSEQ 70
#define SPLIT_SCALE 2048.0f        // 2^11
#define SPLIT_INV   (1.0f / 2048.0f)

// direct global->LDS, 16B per lane; LDS dest is wave-uniform base, HW adds lane*16
__device__ __forceinline__ void gl2lds16(const void* g, void* l) {
  __builtin_amdgcn_global_load_lds(
      (const __attribute__((address_space(1))) void*)g,
      (__attribute__((address_space(3))) void*)l, 16, 0, 0);
}

__device__ __forceinline__ float tanh_fast(float x) {
  float e = __expf(2.0f * x);          // inf-safe: x>>0 -> 1, x<<0 -> -1
  return 1.0f - 2.0f / (e + 1.0f);
}

// H = tanh(A @ W^T + bias), A,W in double-f16 (hi + lo*2^-11 ~ 22-bit capture):
//   acc0 = A0*W0 ; acc1 = A0*W1' + A1'*W0  (primes pre-scaled 2^11)
//   a = acc0 + acc1*2^-11   (dropped A1*W1 term is 2^-22 rel)
// A: [M,K] row-major, W: [1024,K] row-major. Output double-f16 pair.
// 128x128 tile, BK=32, double-buffered LDS (64 KB), 4 waves of 64x64.
// LDS chunk mt (16 rows x 32 k) is lane-linear 16B = exact 16x16x32 A/B frag.
__global__ __launch_bounds__(256, 1) void rnn_step_split(
    const f16* __restrict__ Ah, const f16* __restrict__ Al,
    const f16* __restrict__ Wh, const f16* __restrict__ Wl,
    const float* __restrict__ bias,
    f16* __restrict__ Hh, f16* __restrict__ Hl, int K)
{
  __shared__ __align__(16) f16 sAh[2][128 * 32];
  __shared__ __align__(16) f16 sAl[2][128 * 32];
  __shared__ __align__(16) f16 sWh[2][128 * 32];
  __shared__ __align__(16) f16 sWl[2][128 * 32];

  const int lane = threadIdx.x & 63;
  const int wave = threadIdx.x >> 6;
  const int bm = blockIdx.x;      // M/128
  const int bn = blockIdx.y;      // 8
  const int wr = wave >> 1;
  const int wc = wave & 1;
  const int sr = lane & 15;
  const int sq = lane >> 4;

  const f16* Ahb = Ah + (size_t)(bm * 128) * K;
  const f16* Alb = Al + (size_t)(bm * 128) * K;
  const f16* Whb = Wh + (size_t)(bn * 128) * K;
  const f16* Wlb = Wl + (size_t)(bn * 128) * K;

  f32x4 acc0[4][4], acc1[4][4];
  const f32x4 z4 = {0.f, 0.f, 0.f, 0.f};
#pragma unroll
  for (int i = 0; i < 4; ++i)
#pragma unroll
    for (int j = 0; j < 4; ++j) { acc0[i][j] = z4; acc1[i][j] = z4; }

  const int nk = K >> 5;

#define STAGE(b, kt)                                                        \
  {                                                                         \
    _Pragma("unroll") for (int u = 0; u < 2; ++u) {                         \
      const int mt = wave * 2 + u;                                          \
      const size_t go = (size_t)(mt * 16 + sr) * K + (kt) + sq * 8;         \
      gl2lds16(Ahb + go, &sAh[b][mt * 512]);                                \
      gl2lds16(Alb + go, &sAl[b][mt * 512]);                                \
      gl2lds16(Whb + go, &sWh[b][mt * 512]);                                \
      gl2lds16(Wlb + go, &sWl[b][mt * 512]);                                \
    }                                                                       \
  }

  STAGE(0, 0);

  int buf = 0;
  for (int it = 0; it < nk; ++it, buf ^= 1) {
    __syncthreads();  // drains vmcnt: tile `buf` complete everywhere
    if (it + 1 < nk) STAGE(buf ^ 1, (it + 1) << 5);

    f16x8 vah[4], val[4], vwh[4], vwl[4];
#pragma unroll
    for (int i = 0; i < 4; ++i) {
      vah[i] = *(const f16x8*)&sAh[buf][(wr * 4 + i) * 512 + lane * 8];
      val[i] = *(const f16x8*)&sAl[buf][(wr * 4 + i) * 512 + lane * 8];
      vwh[i] = *(const f16x8*)&sWh[buf][(wc * 4 + i) * 512 + lane * 8];
      vwl[i] = *(const f16x8*)&sWl[buf][(wc * 4 + i) * 512 + lane * 8];
    }
#pragma unroll
    for (int i = 0; i < 4; ++i)
#pragma unroll
      for (int j = 0; j < 4; ++j) {
        acc0[i][j] = __builtin_amdgcn_mfma_f32_16x16x32_f16(vah[i], vwh[j], acc0[i][j], 0, 0, 0);
        acc1[i][j] = __builtin_amdgcn_mfma_f32_16x16x32_f16(vah[i], vwl[j], acc1[i][j], 0, 0, 0);
        acc1[i][j] = __builtin_amdgcn_mfma_f32_16x16x32_f16(val[i], vwh[j], acc1[i][j], 0, 0, 0);
      }
  }
#undef STAGE

  // C/D layout: col=lane&15, row=(lane>>4)*4+reg  [m89-verified]
  const int rq = lane >> 4;
  const int cl = lane & 15;
#pragma unroll
  for (int j = 0; j < 4; ++j) {
    const int gcol = bn * 128 + wc * 64 + j * 16 + cl;
    const float bb = bias[gcol];
#pragma unroll
    for (int i = 0; i < 4; ++i) {
      const int grow = bm * 128 + wr * 64 + i * 16 + rq * 4;
#pragma unroll
      for (int r = 0; r < 4; ++r) {
        const float a = acc0[i][j][r] + acc1[i][j][r] * SPLIT_INV + bb;
        const float t = tanh_fast(a);
        const f16 hi = (f16)t;
        const size_t idx = (size_t)(grow + r) * HID + gcol;
        Hh[idx] = hi;
        Hl[idx] = (f16)((t - (float)hi) * SPLIT_SCALE);  // exact residual, scaled
      }
    }
  }
}

// Y[b,t,:] = H[row,:] @ Who[64,1024]^T + bho (hi-only H: ~2^-11 rel, unamplified)
// step_fix>=0: t=step_fix, b=row (rows=4096); step_fix<0: row=t*4096+b.
__global__ __launch_bounds__(256, 2) void proj_kernel(
    const f16* __restrict__ H, const f16* __restrict__ Who,
    const float* __restrict__ bho, float* __restrict__ Y, int step_fix)
{
  __shared__ __align__(16) f16 As[128 * 64];
  __shared__ __align__(16) f16 Bs[64 * 64];
  const int lane = threadIdx.x & 63;
  const int wave = threadIdx.x >> 6;
  const int bm = blockIdx.x;
  const int sr = lane & 15;
  const int sq = lane >> 4;

  const f16* Hbase = H + (size_t)(bm * 128) * HID;

  f32x4 acc[2][4];
  const f32x4 z4 = {0.f, 0.f, 0.f, 0.f};
#pragma unroll
  for (int i = 0; i < 2; ++i)
#pragma unroll
    for (int j = 0; j < 4; ++j) acc[i][j] = z4;

  for (int kt = 0; kt < HID; kt += 64) {
#pragma unroll
    for (int u = 0; u < 4; ++u) {
      const int cidx = wave * 4 + u;
      const int mt = cidx >> 1, s = cidx & 1;
      gl2lds16(Hbase + (size_t)(mt * 16 + sr) * HID + kt + s * 32 + sq * 8, &As[cidx * 512]);
    }
#pragma unroll
    for (int u = 0; u < 2; ++u) {
      const int cidx = wave * 2 + u;
      const int nt = cidx >> 1, s = cidx & 1;
      gl2lds16(Who + (size_t)(nt * 16 + sr) * HID + kt + s * 32 + sq * 8, &Bs[cidx * 512]);
    }
    __syncthreads();
#pragma unroll
    for (int s = 0; s < 2; ++s) {
      f16x8 af[2], bfr[4];
#pragma unroll
      for (int i = 0; i < 2; ++i)
        af[i] = *(const f16x8*)&As[(((wave * 2 + i) << 1) | s) * 512 + lane * 8];
#pragma unroll
      for (int j = 0; j < 4; ++j)
        bfr[j] = *(const f16x8*)&Bs[((j << 1) | s) * 512 + lane * 8];
#pragma unroll
      for (int i = 0; i < 2; ++i)
#pragma unroll
        for (int j = 0; j < 4; ++j)
          acc[i][j] = __builtin_amdgcn_mfma_f32_16x16x32_f16(af[i], bfr[j], acc[i][j], 0, 0, 0);
    }
    __syncthreads();
  }

  const int rq = lane >> 4;
  const int cl = lane & 15;
#pragma unroll
  for (int j = 0; j < 4; ++j) {
    const int col = j * 16 + cl;
    const float bb = bho[col];
#pragma unroll
    for (int i = 0; i < 2; ++i)
#pragma unroll
      for (int r = 0; r < 4; ++r) {
        const int row = bm * 128 + wave * 32 + i * 16 + rq * 4 + r;
        int t, b;
        if (step_fix >= 0) { t = step_fix; b = row; }
        else               { t = row >> 12; b = row & 4095; }
        Y[((size_t)b * TSEQ + t) * OBS + col] = acc[i][j][r] + bb;
      }
  }
}

__global__ void cast_kernel(const float* __restrict__ x, f16* __restrict__ y, int n) {
  int i = blockIdx.x * blockDim.x + threadIdx.x;
  if (i < n) y[i] = (f16)x[i];
}

__global__ void split_kernel(const float* __restrict__ x, f16* __restrict__ hi,
                             f16* __restrict__ lo, int n) {
  int i = blockIdx.x * blockDim.x + threadIdx.x;
  if (i < n) {
    float v = x[i];
    f16 h = (f16)v;
    hi[i] = h;
    lo[i] = (f16)((v - (float)h) * SPLIT_SCALE);
  }
}

// Weff[n,k] = Whh[n,k] + sum_o Wih[n,o]*Who[o,k]  (fp32, then double-f16 split)
__global__ void prep_weff(const float* __restrict__ Whh, const float* __restrict__ Wih,
                          const float* __restrict__ Who,
                          f16* __restrict__ Wh, f16* __restrict__ Wl) {
  const int n = blockIdx.x;
  __shared__ float wih_row[OBS];
  if (threadIdx.x < OBS) wih_row[threadIdx.x] = Wih[n * OBS + threadIdx.x];
  __syncthreads();
  for (int k = threadIdx.x; k < HID; k += 256) {
    float s = Whh[(size_t)n * HID + k];
#pragma unroll 8
    for (int o = 0; o < OBS; ++o) s = fmaf(wih_row[o], Who[(size_t)o * HID + k], s);
    const size_t idx = (size_t)n * HID + k;
    f16 h = (f16)s;
    Wh[idx] = h;
    Wl[idx] = (f16)((s - (float)h) * SPLIT_SCALE);
  }
}

// W1[n,j] = sum_k Whh[n,k]*Wl2h[k,j]  (fp32, then double-f16 split)
__global__ void prep_w1(const float* __restrict__ Whh, const float* __restrict__ Wl2h,
                        f16* __restrict__ W1h, f16* __restrict__ W1l) {
  const int n = blockIdx.x, j = threadIdx.x;  // block=128
  float s = 0.f;
  for (int k = 0; k < HID; ++k) s = fmaf(Whh[(size_t)n * HID + k], Wl2h[(size_t)k * LAT + j], s);
  const size_t idx = (size_t)n * LAT + j;
  f16 h = (f16)s;
  W1h[idx] = h;
  W1l[idx] = (f16)((s - (float)h) * SPLIT_SCALE);
}

// beff[n] = bih+bhh + Wih@bho ; b1[n] = bih+bhh + Whh@bl2h
__global__ void prep_bias(const float* __restrict__ bih, const float* __restrict__ bhh,
                          const float* __restrict__ bho, const float* __restrict__ Wih,
                          const float* __restrict__ Whh, const float* __restrict__ bl2h,
                          float* __restrict__ beff, float* __restrict__ b1) {
  const int n = blockIdx.x, l = threadIdx.x;  // block=64, one wave
  float s1 = Wih[(size_t)n * OBS + l] * bho[l];
  float s2 = 0.f;
  for (int k = l; k < HID; k += 64) s2 = fmaf(Whh[(size_t)n * HID + k], bl2h[k], s2);
#pragma unroll
  for (int off = 32; off > 0; off >>= 1) {
    s1 += __shfl_down(s1, off);
    s2 += __shfl_down(s2, off);
  }
  if (l == 0) {
    const float base = bih[n] + bhh[n];
    beff[n] = base + s1;
    b1[n]   = base + s2;
  }
}

extern "C" void kernel_launch(void* const* d_in, const int* in_sizes, int n_in,
                              void* d_out, int out_size, void* d_ws, size_t ws_size,
                              hipStream_t stream) {
  (void)in_sizes; (void)n_in; (void)out_size;
  const float* z    = (const float*)d_in[0];
  const float* Wl2h = (const float*)d_in[1];
  const float* bl2h = (const float*)d_in[2];
  const float* Wih  = (const float*)d_in[3];
  const float* bih  = (const float*)d_in[4];
  const float* Whh  = (const float*)d_in[5];
  const float* bhh  = (const float*)d_in[6];
  const float* Who  = (const float*)d_in[7];
  const float* bho  = (const float*)d_in[8];
  float* Y = (float*)d_out;

  char* ws = (char*)d_ws;
  size_t off = 0;
  auto take = [&](size_t bytes) {
    char* p = ws + off;
    off = (off + bytes + 255) & ~(size_t)255;
    return p;
  };
  f16*   Weffh = (f16*)take((size_t)HID * HID * 2);
  f16*   Weffl = (f16*)take((size_t)HID * HID * 2);
  f16*   W1h   = (f16*)take((size_t)HID * LAT * 2);
  f16*   W1l   = (f16*)take((size_t)HID * LAT * 2);
  f16*   Whob  = (f16*)take((size_t)OBS * HID * 2);
  f16*   zh    = (f16*)take((size_t)B_SZ * LAT * 2);
  f16*   zl    = (f16*)take((size_t)B_SZ * LAT * 2);
  float* beff  = (float*)take(HID * 4);
  float* b1    = (float*)take(HID * 4);

  const size_t SLICE = (size_t)B_SZ * HID;  // elems per h-slice
  f16* Hlo = (f16*)take(2 * SLICE * 2);     // lo state, double-buffered
  const bool big = ws_size >= off + (size_t)TSEQ * SLICE * 2 + 256;
  f16* Hhi = (f16*)take((big ? (size_t)TSEQ : 2) * SLICE * 2);

  split_kernel<<<(B_SZ * LAT) / 256, 256, 0, stream>>>(z, zh, zl, B_SZ * LAT);
  cast_kernel<<<(OBS * HID) / 256, 256, 0, stream>>>(Who, Whob, OBS * HID);
  prep_weff<<<HID, 256, 0, stream>>>(Whh, Wih, Who, Weffh, Weffl);
  prep_w1<<<HID, LAT, 0, stream>>>(Whh, Wl2h, W1h, W1l);
  prep_bias<<<HID, 64, 0, stream>>>(bih, bhh, bho, Wih, Whh, bl2h, beff, b1);

  dim3 sgrid(B_SZ / 128, HID / 128);
  // t = 0: h_1 = tanh(z @ W1^T + b1)
  f16* ph = Hhi;
  f16* pl = Hlo;
  rnn_step_split<<<sgrid, 256, 0, stream>>>(zh, zl, W1h, W1l, b1, ph, pl, LAT);
  if (!big) proj_kernel<<<B_SZ / 128, 256, 0, stream>>>(ph, Whob, bho, Y, 0);
  for (int t = 1; t < TSEQ; ++t) {
    f16* ch  = big ? (Hhi + (size_t)t * SLICE) : (Hhi + (size_t)(t & 1) * SLICE);
    f16* cle = Hlo + (size_t)(t & 1) * SLICE;
    rnn_step_split<<<sgrid, 256, 0, stream>>>(ph, pl, Weffh, Weffl, beff, ch, cle, HID);
    if (!big) proj_kernel<<<B_SZ / 128, 256, 0, stream>>>(ch, Whob, bho, Y, t);
    ph = ch;
    pl = cle;
  }
  if (big) proj_kernel<<<(TSEQ * B_SZ) / 128, 256, 0, stream>>>(Hhi, Whob, bho, Y, -1);
}